// Round 10
// baseline (129.108 us; speedup 1.0000x reference)
//
#include <hip/hip_runtime.h>

#define BB 256
#define TT 1024
#define VV 64
#define LL 64
#define LOG2E 1.4426950408889634f
#define LN2   0.6931471805599453f

__device__ __forceinline__ int   f2i(float x) { return __float_as_int(x); }
__device__ __forceinline__ float i2f(int x)   { return __int_as_float(x); }

// wave-wide max of non-negative values (0 identity), result broadcast
__device__ __forceinline__ float wave_max63(float x) {
  x = fmaxf(x, i2f(__builtin_amdgcn_update_dpp(0, f2i(x), 0x111, 0xF, 0xF, true)));
  x = fmaxf(x, i2f(__builtin_amdgcn_update_dpp(0, f2i(x), 0x112, 0xF, 0xF, true)));
  x = fmaxf(x, i2f(__builtin_amdgcn_update_dpp(0, f2i(x), 0x114, 0xF, 0xF, true)));
  x = fmaxf(x, i2f(__builtin_amdgcn_update_dpp(0, f2i(x), 0x118, 0xF, 0xF, true)));
  x = fmaxf(x, i2f(__builtin_amdgcn_update_dpp(0, f2i(x), 0x142, 0xF, 0xF, true)));
  x = fmaxf(x, i2f(__builtin_amdgcn_update_dpp(0, f2i(x), 0x143, 0xF, 0xF, true)));
  return i2f(__builtin_amdgcn_readlane(f2i(x), 63));
}

// async 4B/lane global->LDS DMA: LDS dest = uniform base + lane*4; global
// source is PER-LANE (this is the un-sinkable prefetch -- a side-effecting
// instruction the compiler cannot rematerialize next to the use).
__device__ __forceinline__ void gload4(const float* g, float* l) {
  __builtin_amdgcn_global_load_lds(
      (const __attribute__((address_space(1))) unsigned int*)g,
      (__attribute__((address_space(3))) unsigned int*)l, 4, 0, 0);
}

// ---------- R10: fwd/bwd DP fed by REAL DMA prefetch, one kernel, 6 waves ----------
// R4's VGPR_Count=56 proves the 3-window register ring (51 live floats) never
// existed: the compiler sank the plain loads to their uses, so every DP window
// paid full memory latency -- the structure-insensitive ~100cy/step floor of
// R4-R9. R10 feeds each DP wave from its own 4-slot LDS ring via per-lane-
// source global_load_lds (17 DMAs/window: 16 g-rows + 1 c-row), 3 windows in
// flight (51 <= vmcnt cap 63), one bare counted s_waitcnt vmcnt(34) +
// sched_barrier(0) per window (T3/T4: never drain in-loop). No loop barriers:
// single-wave self-sync via vmcnt. c now arrives via LDS broadcast -- the
// 16-deep readlane chain is gone. DP math verbatim from R7 (absmax 32.0):
// renorm 2^60, RESCALE45 combine, p-clamp; LSE waves verbatim R7.
extern "C" __global__ void __launch_bounds__(384, 1)
ctc_fused(const int* __restrict__ labels, const float* __restrict__ logits,
          const int* __restrict__ mask, float* __restrict__ out) {
  __shared__ __align__(16) float gFl[4][16][64];   // fwd g ring, 16 KB
  __shared__ __align__(16) float cFl[4][64];       // fwd c ring,  1 KB
  __shared__ __align__(16) float gBl[4][16][64];   // bwd g ring, 16 KB
  __shared__ __align__(16) float cBl[4][64];       // bwd c ring,  1 KB
  __shared__ float lsePart[4];
  __shared__ float sG0v[64], sG1v[64];
  __shared__ float sG2s;
  __shared__ int   sCtB;
  const int b = blockIdx.x;
  const int tid = threadIdx.x;
  const int lane = tid & 63;
  const int wv = tid >> 6;

  const float* lg = logits + (size_t)b * TT * VV;

  // every wave computes len (redundant, preamble-only)
  int lsum = 0;
  const int* mrow = mask + b * TT;
#pragma unroll
  for (int k = 0; k < TT / 64; ++k) lsum += mrow[lane + (k << 6)];
#pragma unroll
  for (int off = 32; off; off >>= 1) lsum += __shfl_xor(lsum, off);
  int len = __builtin_amdgcn_readfirstlane(lsum);
  len = len < 1 ? 1 : (len > TT ? TT : len);
  const int nwin = (len + 15) >> 4;
  int mid = len >> 1; mid = mid < 1 ? 1 : mid;
  const int nwF = (mid + 15) >> 4;           // fwd windows: rows [0, mid); <= 32
  const int nwB = (len - mid + 15) >> 4;     // bwd windows: rows [len-1, mid]; <= 32

  int lab_len = 0;
  float A0 = 0.0f, A1 = 0.0f, A2 = 0.0f;
  int ctotA = 0;

#define RENORM3(X, Y, Z, CT) { \
    const float mxv = wave_max63(fmaxf(fmaxf(X, Y), Z)); \
    const int eb_ = (f2i(mxv) >> 23) & 255; \
    int kk = (eb_ > 0 && eb_ < 255) ? (187 - eb_) : 0; \
    kk = kk > 126 ? 126 : (kk < -126 ? -126 : kk); \
    CT += kk; \
    const float sc = i2f((127 + kk) << 23); \
    X *= sc; Y *= sc; Z *= sc; \
  }

#define RESCALE45(X, Y, Z, CT) { \
    const float mxv = wave_max63(fmaxf(fmaxf(X, Y), Z)); \
    const int eb_ = (f2i(mxv) >> 23) & 255; \
    int kk = (eb_ > 0 && eb_ < 255) ? (172 - eb_) : 0; \
    kk = kk > 126 ? 126 : (kk < -126 ? -126 : kk); \
    CT += kk; \
    const float sc = i2f((127 + kk) << 23); \
    X *= sc; Y *= sc; Z *= sc; \
  }

  if (wv == 0) {
    // ================= forward DP wave: rows [0, mid), DMA-fed =================
    const int lab = labels[b * LL + lane] & 63;   // label for state 2*lane+1
    lab_len = (int)__popcll(__ballot(lab != 0));
    const int plab = __builtin_amdgcn_update_dpp(0, lab, 0x138, 0xF, 0xF, false);
    const float sk = (lab != 0 && lab != plab) ? 1.0f : 0.0f; // allow_skip
    A0 = (lane == 0) ? 1.0f : 0.0f;               // t=0 runs as a normal step
    __builtin_amdgcn_s_setprio(1);

    const int cu = lane & 15;
    const float* lgg = lg + lab;                  // per-lane gather base

    // 17 DMAs per window. Max prefetched row = (nwF+2)*16+15 <= 559 < 1024:
    // always in-bounds, no guards (rows past len hold valid random data;
    // masked steps discard them -- same as R4-R9).
#define FDMA(WN) { \
    const int rw_ = (WN) << 4; const int sl_ = (WN) & 3; \
    gload4(lgg + ((rw_ + 0)  << 6), &gFl[sl_][0][0]);  \
    gload4(lgg + ((rw_ + 1)  << 6), &gFl[sl_][1][0]);  \
    gload4(lgg + ((rw_ + 2)  << 6), &gFl[sl_][2][0]);  \
    gload4(lgg + ((rw_ + 3)  << 6), &gFl[sl_][3][0]);  \
    gload4(lgg + ((rw_ + 4)  << 6), &gFl[sl_][4][0]);  \
    gload4(lgg + ((rw_ + 5)  << 6), &gFl[sl_][5][0]);  \
    gload4(lgg + ((rw_ + 6)  << 6), &gFl[sl_][6][0]);  \
    gload4(lgg + ((rw_ + 7)  << 6), &gFl[sl_][7][0]);  \
    gload4(lgg + ((rw_ + 8)  << 6), &gFl[sl_][8][0]);  \
    gload4(lgg + ((rw_ + 9)  << 6), &gFl[sl_][9][0]);  \
    gload4(lgg + ((rw_ + 10) << 6), &gFl[sl_][10][0]); \
    gload4(lgg + ((rw_ + 11) << 6), &gFl[sl_][11][0]); \
    gload4(lgg + ((rw_ + 12) << 6), &gFl[sl_][12][0]); \
    gload4(lgg + ((rw_ + 13) << 6), &gFl[sl_][13][0]); \
    gload4(lgg + ((rw_ + 14) << 6), &gFl[sl_][14][0]); \
    gload4(lgg + ((rw_ + 15) << 6), &gFl[sl_][15][0]); \
    gload4(lg + ((rw_ + cu) << 6),  &cFl[sl_][0]);     \
  }

#define FSTEPU(U) { \
    const float A1p = i2f(__builtin_amdgcn_update_dpp(0, f2i(A1), 0x138, 0xF, 0xF, false)); \
    const float nA0 = c##U * (A0 + A1p); \
    const float nA1 = g##U * fmaf(sk, A1p, A0 + A1); \
    A2 = c##U * (A2 + A1); \
    A0 = nA0; A1 = nA1; \
  }

#define FSTEPM(U) { \
    const float A1p = i2f(__builtin_amdgcn_update_dpp(0, f2i(A1), 0x138, 0xF, 0xF, false)); \
    const float nA0 = c##U * (A0 + A1p); \
    const float nA1 = g##U * fmaf(sk, A1p, A0 + A1); \
    const float nA2 = c##U * (A2 + A1); \
    const bool act = (tbase + (U)) < mid; \
    A0 = act ? nA0 : A0; A1 = act ? nA1 : A1; A2 = act ? nA2 : A2; \
  }

    // prologue: queue windows 0-2 (51 DMAs in flight)
    FDMA(0) FDMA(1) FDMA(2)

    for (int w = 0; w < nwF; ++w) {
      // counted wait: window w's 17 DMAs landed; w+1/w+2 stay in flight.
      asm volatile("s_waitcnt vmcnt(34)");
      __builtin_amdgcn_sched_barrier(0);
      FDMA(w + 3)                       // refill slot (w-1)&3, consumed last iter
      const int sl = w & 3;
      const float* gr = &gFl[sl][0][0] + lane;
      float g0  = gr[0],    g1  = gr[64],   g2  = gr[128],  g3  = gr[192],
            g4  = gr[256],  g5  = gr[320],  g6  = gr[384],  g7  = gr[448],
            g8  = gr[512],  g9  = gr[576],  g10 = gr[640],  g11 = gr[704],
            g12 = gr[768],  g13 = gr[832],  g14 = gr[896],  g15 = gr[960];
      const float4* cp = (const float4*)&cFl[sl][0];
      const float4 ca = cp[0], cb = cp[1], cc = cp[2], cd = cp[3];
      g0  = __builtin_amdgcn_exp2f(g0  * LOG2E); g1  = __builtin_amdgcn_exp2f(g1  * LOG2E);
      g2  = __builtin_amdgcn_exp2f(g2  * LOG2E); g3  = __builtin_amdgcn_exp2f(g3  * LOG2E);
      g4  = __builtin_amdgcn_exp2f(g4  * LOG2E); g5  = __builtin_amdgcn_exp2f(g5  * LOG2E);
      g6  = __builtin_amdgcn_exp2f(g6  * LOG2E); g7  = __builtin_amdgcn_exp2f(g7  * LOG2E);
      g8  = __builtin_amdgcn_exp2f(g8  * LOG2E); g9  = __builtin_amdgcn_exp2f(g9  * LOG2E);
      g10 = __builtin_amdgcn_exp2f(g10 * LOG2E); g11 = __builtin_amdgcn_exp2f(g11 * LOG2E);
      g12 = __builtin_amdgcn_exp2f(g12 * LOG2E); g13 = __builtin_amdgcn_exp2f(g13 * LOG2E);
      g14 = __builtin_amdgcn_exp2f(g14 * LOG2E); g15 = __builtin_amdgcn_exp2f(g15 * LOG2E);
      const float c0  = __builtin_amdgcn_exp2f(ca.x * LOG2E);
      const float c1  = __builtin_amdgcn_exp2f(ca.y * LOG2E);
      const float c2  = __builtin_amdgcn_exp2f(ca.z * LOG2E);
      const float c3  = __builtin_amdgcn_exp2f(ca.w * LOG2E);
      const float c4  = __builtin_amdgcn_exp2f(cb.x * LOG2E);
      const float c5  = __builtin_amdgcn_exp2f(cb.y * LOG2E);
      const float c6  = __builtin_amdgcn_exp2f(cb.z * LOG2E);
      const float c7  = __builtin_amdgcn_exp2f(cb.w * LOG2E);
      const float c8  = __builtin_amdgcn_exp2f(cc.x * LOG2E);
      const float c9  = __builtin_amdgcn_exp2f(cc.y * LOG2E);
      const float c10 = __builtin_amdgcn_exp2f(cc.z * LOG2E);
      const float c11 = __builtin_amdgcn_exp2f(cc.w * LOG2E);
      const float c12 = __builtin_amdgcn_exp2f(cd.x * LOG2E);
      const float c13 = __builtin_amdgcn_exp2f(cd.y * LOG2E);
      const float c14 = __builtin_amdgcn_exp2f(cd.z * LOG2E);
      const float c15 = __builtin_amdgcn_exp2f(cd.w * LOG2E);
      RENORM3(A0, A1, A2, ctotA)
      const int tbase = w << 4;
      if (tbase + 16 <= mid) {
        FSTEPU(0)  FSTEPU(1)  FSTEPU(2)  FSTEPU(3)  FSTEPU(4)  FSTEPU(5)  FSTEPU(6)  FSTEPU(7)
        FSTEPU(8)  FSTEPU(9)  FSTEPU(10) FSTEPU(11) FSTEPU(12) FSTEPU(13) FSTEPU(14) FSTEPU(15)
      } else {
        FSTEPM(0)  FSTEPM(1)  FSTEPM(2)  FSTEPM(3)  FSTEPM(4)  FSTEPM(5)  FSTEPM(6)  FSTEPM(7)
        FSTEPM(8)  FSTEPM(9)  FSTEPM(10) FSTEPM(11) FSTEPM(12) FSTEPM(13) FSTEPM(14) FSTEPM(15)
      }
    }
    // drain own DMAs before the block-wide sync (LDS dealloc hazard)
    asm volatile("s_waitcnt vmcnt(0)");
    __builtin_amdgcn_sched_barrier(0);
    RESCALE45(A0, A1, A2, ctotA)
#undef FSTEPM
#undef FSTEPU
#undef FDMA

  } else if (wv == 1) {
    // ================= backward DP wave: rows [len-1, mid], DMA-fed =================
    const int lab = labels[b * LL + lane] & 63;
    const int ll = (int)__popcll(__ballot(lab != 0));
    const int plab = __builtin_amdgcn_update_dpp(0, lab, 0x138, 0xF, 0xF, false);
    const float sk = (lab != 0 && lab != plab) ? 1.0f : 0.0f;
    const float skp = i2f(__builtin_amdgcn_update_dpp(0, f2i(sk), 0x130, 0xF, 0xF, false)); // sk[l+1]
    const bool is63 = (lane == 63);
    __builtin_amdgcn_s_setprio(1);

    // gamma seeds at t = len: [s==e] + [s==max(e-1,0)], e = 2*ll
    float G0 = 0.0f, G1 = 0.0f, G2 = 0.0f;
    if (ll == 0)            { G0 = (lane == 0) ? 2.0f : 0.0f; }
    else if (ll >= LL)      { G2 = 1.0f; G1 = is63 ? 1.0f : 0.0f; }
    else {
      G0 = (lane == ll) ? 1.0f : 0.0f;
      G1 = (lane == ll - 1) ? 1.0f : 0.0f;
    }
    int ctotB = 0;

    const int cu = lane & 15;
    const float* lgg = lg + lab;

#define BLD(RW) ( (RW) < 0 ? 0 : (RW) )
#define BDMA(JN) { \
    const int br_ = len - 1 - ((JN) << 4); const int sl_ = (JN) & 3; \
    gload4(lgg + (BLD(br_ - 0)  << 6), &gBl[sl_][0][0]);  \
    gload4(lgg + (BLD(br_ - 1)  << 6), &gBl[sl_][1][0]);  \
    gload4(lgg + (BLD(br_ - 2)  << 6), &gBl[sl_][2][0]);  \
    gload4(lgg + (BLD(br_ - 3)  << 6), &gBl[sl_][3][0]);  \
    gload4(lgg + (BLD(br_ - 4)  << 6), &gBl[sl_][4][0]);  \
    gload4(lgg + (BLD(br_ - 5)  << 6), &gBl[sl_][5][0]);  \
    gload4(lgg + (BLD(br_ - 6)  << 6), &gBl[sl_][6][0]);  \
    gload4(lgg + (BLD(br_ - 7)  << 6), &gBl[sl_][7][0]);  \
    gload4(lgg + (BLD(br_ - 8)  << 6), &gBl[sl_][8][0]);  \
    gload4(lgg + (BLD(br_ - 9)  << 6), &gBl[sl_][9][0]);  \
    gload4(lgg + (BLD(br_ - 10) << 6), &gBl[sl_][10][0]); \
    gload4(lgg + (BLD(br_ - 11) << 6), &gBl[sl_][11][0]); \
    gload4(lgg + (BLD(br_ - 12) << 6), &gBl[sl_][12][0]); \
    gload4(lgg + (BLD(br_ - 13) << 6), &gBl[sl_][13][0]); \
    gload4(lgg + (BLD(br_ - 14) << 6), &gBl[sl_][14][0]); \
    gload4(lgg + (BLD(br_ - 15) << 6), &gBl[sl_][15][0]); \
    gload4(lg + (BLD(br_ - cu) << 6),  &cBl[sl_][0]);     \
  }

#define BSTEPU(U) { \
    const float V_ = i2f(__builtin_amdgcn_update_dpp(0, f2i(G1), 0x130, 0xF, 0xF, false)); \
    float U_ = i2f(__builtin_amdgcn_update_dpp(0, f2i(G0), 0x130, 0xF, 0xF, false)); \
    U_ = is63 ? G2 : U_; \
    const float nG0 = fmaf(cB##U, G0, gB##U * G1); \
    const float nG1 = fmaf(gB##U, G1, fmaf(cB##U, U_, hB##U * V_)); \
    G2 = cB##U * G2; \
    G0 = nG0; G1 = nG1; \
  }

#define BSTEPM(U) { \
    const float V_ = i2f(__builtin_amdgcn_update_dpp(0, f2i(G1), 0x130, 0xF, 0xF, false)); \
    float U_ = i2f(__builtin_amdgcn_update_dpp(0, f2i(G0), 0x130, 0xF, 0xF, false)); \
    U_ = is63 ? G2 : U_; \
    const float nG0 = fmaf(cB##U, G0, gB##U * G1); \
    const float nG1 = fmaf(gB##U, G1, fmaf(cB##U, U_, hB##U * V_)); \
    const float nG2 = cB##U * G2; \
    const bool act = (brow0 - (U)) >= mid; \
    G0 = act ? nG0 : G0; G1 = act ? nG1 : G1; G2 = act ? nG2 : G2; \
  }

#define BPREP(U) \
    const float gB##U = __builtin_amdgcn_exp2f(r##U * LOG2E); \
    const float hB##U = skp * i2f(__builtin_amdgcn_update_dpp(0, f2i(gB##U), 0x130, 0xF, 0xF, false));

    BDMA(0) BDMA(1) BDMA(2)

    for (int j = 0; j < nwB; ++j) {
      asm volatile("s_waitcnt vmcnt(34)");
      __builtin_amdgcn_sched_barrier(0);
      BDMA(j + 3)
      const int sl = j & 3;
      const int brow0 = len - 1 - (j << 4);
      const float* gr = &gBl[sl][0][0] + lane;
      const float r0  = gr[0],    r1  = gr[64],   r2  = gr[128],  r3  = gr[192],
                  r4  = gr[256],  r5  = gr[320],  r6  = gr[384],  r7  = gr[448],
                  r8  = gr[512],  r9  = gr[576],  r10 = gr[640],  r11 = gr[704],
                  r12 = gr[768],  r13 = gr[832],  r14 = gr[896],  r15 = gr[960];
      const float4* cp = (const float4*)&cBl[sl][0];
      const float4 ca = cp[0], cb = cp[1], cc = cp[2], cd = cp[3];
      BPREP(0)  BPREP(1)  BPREP(2)  BPREP(3)  BPREP(4)  BPREP(5)  BPREP(6)  BPREP(7)
      BPREP(8)  BPREP(9)  BPREP(10) BPREP(11) BPREP(12) BPREP(13) BPREP(14) BPREP(15)
      const float cB0  = __builtin_amdgcn_exp2f(ca.x * LOG2E);
      const float cB1  = __builtin_amdgcn_exp2f(ca.y * LOG2E);
      const float cB2  = __builtin_amdgcn_exp2f(ca.z * LOG2E);
      const float cB3  = __builtin_amdgcn_exp2f(ca.w * LOG2E);
      const float cB4  = __builtin_amdgcn_exp2f(cb.x * LOG2E);
      const float cB5  = __builtin_amdgcn_exp2f(cb.y * LOG2E);
      const float cB6  = __builtin_amdgcn_exp2f(cb.z * LOG2E);
      const float cB7  = __builtin_amdgcn_exp2f(cb.w * LOG2E);
      const float cB8  = __builtin_amdgcn_exp2f(cc.x * LOG2E);
      const float cB9  = __builtin_amdgcn_exp2f(cc.y * LOG2E);
      const float cB10 = __builtin_amdgcn_exp2f(cc.z * LOG2E);
      const float cB11 = __builtin_amdgcn_exp2f(cc.w * LOG2E);
      const float cB12 = __builtin_amdgcn_exp2f(cd.x * LOG2E);
      const float cB13 = __builtin_amdgcn_exp2f(cd.y * LOG2E);
      const float cB14 = __builtin_amdgcn_exp2f(cd.z * LOG2E);
      const float cB15 = __builtin_amdgcn_exp2f(cd.w * LOG2E);
      RENORM3(G0, G1, G2, ctotB)
      if (brow0 - 15 >= mid) {
        BSTEPU(0)  BSTEPU(1)  BSTEPU(2)  BSTEPU(3)  BSTEPU(4)  BSTEPU(5)  BSTEPU(6)  BSTEPU(7)
        BSTEPU(8)  BSTEPU(9)  BSTEPU(10) BSTEPU(11) BSTEPU(12) BSTEPU(13) BSTEPU(14) BSTEPU(15)
      } else {
        BSTEPM(0)  BSTEPM(1)  BSTEPM(2)  BSTEPM(3)  BSTEPM(4)  BSTEPM(5)  BSTEPM(6)  BSTEPM(7)
        BSTEPM(8)  BSTEPM(9)  BSTEPM(10) BSTEPM(11) BSTEPM(12) BSTEPM(13) BSTEPM(14) BSTEPM(15)
      }
    }
    asm volatile("s_waitcnt vmcnt(0)");
    __builtin_amdgcn_sched_barrier(0);
    RESCALE45(G0, G1, G2, ctotB)
#undef BPREP
#undef BSTEPM
#undef BSTEPU
#undef BDMA
#undef BLD

    sG0v[lane] = G0;
    sG1v[lane] = G1;
    if (is63) sG2s = G2;
    if (lane == 0) sCtB = ctotB;

  } else {
    // ================= LSE waves (2..5): async row-LSE streaming (R7 verbatim) =================
    const int pw = wv - 2;
    const int prow = lane >> 4;
    const int pcol = (lane & 15) << 2;
    const float* pb_ = lg + ((((pw << 2) + prow) << 6) + pcol);
    float acc = 0.0f;
    float4 pa, pb, pc;

#define LISSUE(K, S) { S = *(const float4*)(pb_ + ((K) << 10)); }

#define LBODY(K, S) { \
    const float e0 = __builtin_amdgcn_exp2f(S.x * LOG2E); \
    const float e1 = __builtin_amdgcn_exp2f(S.y * LOG2E); \
    const float e2 = __builtin_amdgcn_exp2f(S.z * LOG2E); \
    const float e3 = __builtin_amdgcn_exp2f(S.w * LOG2E); \
    if ((K) + 3 < 64) { LISSUE((K) + 3, S) } \
    float s = (e0 + e1) + (e2 + e3); \
    s += i2f(__builtin_amdgcn_update_dpp(0, f2i(s), 0x111, 0xF, 0xF, true)); \
    s += i2f(__builtin_amdgcn_update_dpp(0, f2i(s), 0x112, 0xF, 0xF, true)); \
    s += i2f(__builtin_amdgcn_update_dpp(0, f2i(s), 0x114, 0xF, 0xF, true)); \
    s += i2f(__builtin_amdgcn_update_dpp(0, f2i(s), 0x118, 0xF, 0xF, true)); \
    if ((lane & 15) == 15 && ((((K) << 4) + (pw << 2) + prow) < len)) acc += __logf(s); \
  }

    LISSUE(0, pa) LISSUE(1, pb) LISSUE(2, pc)
    int k = 0;
    for (; k + 3 <= nwin; k += 3) {
      LBODY(k, pa) LBODY(k + 1, pb) LBODY(k + 2, pc)
    }
    if (k < nwin) { LBODY(k, pa) ++k; }
    if (k < nwin) { LBODY(k, pb) ++k; }
#undef LBODY
#undef LISSUE

    float a = ((lane & 15) == 15) ? acc : 0.0f;
    a += __shfl_xor(a, 16);
    a += __shfl_xor(a, 32);
    if (lane == 63) lsePart[pw] = a;
  }

  __syncthreads();   // single block-wide sync of the whole kernel

  if (wv == 0) {
    // p = sum_s alpha_{mid-1}(s) * gamma_mid(s); both rescaled to <= 2^45
    float prod = A0 * sG0v[lane] + A1 * sG1v[lane];
    if (lane == 63) prod = fmaf(A2, sG2s, prod);
#pragma unroll
    for (int off = 32; off; off >>= 1) prod += __shfl_xor(prod, off);
    const float p = fmaxf(prod, 1e-37f);   // guard: never log(0) -> inf poisoning
    float loss = ((lsePart[0] + lsePart[1]) + (lsePart[2] + lsePart[3]))
               - LN2 * (__builtin_amdgcn_logf(p) - (float)(ctotA + sCtB));
    if (lab_len > len) loss = 0.0f;  // feasibility mask
    if (lane == 0) atomicAdd(out, loss * (1.0f / 256.0f));
  }
#undef RESCALE45
#undef RENORM3
}

extern "C" void kernel_launch(void* const* d_in, const int* in_sizes, int n_in,
                              void* d_out, int out_size, void* d_ws, size_t ws_size,
                              hipStream_t stream) {
  (void)in_sizes; (void)n_in; (void)out_size; (void)d_ws; (void)ws_size;
  hipMemsetAsync(d_out, 0, sizeof(float), stream);   // d_out is poisoned 0xAA
  ctc_fused<<<dim3(BB), dim3(384), 0, stream>>>(
      (const int*)d_in[0], (const float*)d_in[1], (const int*)d_in[2], (float*)d_out);
}

// Round 11
// 112.490 us; speedup vs baseline: 1.1477x; 1.1477x over previous
//
#include <hip/hip_runtime.h>

#define BB 256
#define TT 1024
#define VV 64
#define LL 64
#define LOG2E 1.4426950408889634f
#define LN2   0.6931471805599453f

__device__ __forceinline__ int   f2i(float x) { return __float_as_int(x); }
__device__ __forceinline__ float i2f(int x)   { return __int_as_float(x); }

// wave-wide max of non-negative values (0 identity), result broadcast
__device__ __forceinline__ float wave_max63(float x) {
  x = fmaxf(x, i2f(__builtin_amdgcn_update_dpp(0, f2i(x), 0x111, 0xF, 0xF, true)));
  x = fmaxf(x, i2f(__builtin_amdgcn_update_dpp(0, f2i(x), 0x112, 0xF, 0xF, true)));
  x = fmaxf(x, i2f(__builtin_amdgcn_update_dpp(0, f2i(x), 0x114, 0xF, 0xF, true)));
  x = fmaxf(x, i2f(__builtin_amdgcn_update_dpp(0, f2i(x), 0x118, 0xF, 0xF, true)));
  x = fmaxf(x, i2f(__builtin_amdgcn_update_dpp(0, f2i(x), 0x142, 0xF, 0xF, true)));
  x = fmaxf(x, i2f(__builtin_amdgcn_update_dpp(0, f2i(x), 0x143, 0xF, 0xF, true)));
  return i2f(__builtin_amdgcn_readlane(f2i(x), 63));
}

// ---------- R11: fwd + REVERSED-FORWARD split (both waves run the cheap fwd code) ----------
// R7 timeline: fwd half ~1.7k cy/window (R4-measured), bwd half ~2.1-3k -- the
// mirrored gamma recurrence carries 2 on-chain DPPs/step + 16 BPREP DPP-muls
// per window, making it the long pole and eating the split's gain. R11: the
// suffix DP IS the forward DP of the time-reversed, label-reversed problem:
//   p = sum_s' abar_mid(s') * arev_{len-1-mid}(2*ll - s')
// where abar = fwd alpha pushed through ONE emission-free transition (epilogue
// -only: abar(2l)=A0+A1[l-1]; abar(2l+1)=A1+A0+sk*A1[l-1]; abar(128)=A2+A1[63])
// and arev is produced by the byte-identical FBODY on reversed labels
// (rlab[l]=lab[ll-1-l]) and descending rows (negative compile-time offsets).
// Seed A0[0] = (ll==0 ? 2 : 1) encodes the reference's logaddexp(a_e,a_{e-1})
// (incl. the ll==0 double-count, same as R7's validated gamma-seed 2.0). The
// combine mirrors states via LDS index-reverse; ll==64 corner pairs A2<->A0'
// through sG2s/sG0v[0]. Verified by hand on the ll=1,len=2,mid=1 toy case.
// Feeding stays R4/R7-style sunk plain loads (fastest measured; R10's DMA
// regressed). fwd wave, LSE waves, renorm 2^60, RESCALE45, p-clamp: R7 verbatim.
extern "C" __global__ void __launch_bounds__(384, 1)
ctc_fused(const int* __restrict__ labels, const float* __restrict__ logits,
          const int* __restrict__ mask, float* __restrict__ out) {
  __shared__ float lsePart[4];
  __shared__ float sG0v[64], sG1v[64];
  __shared__ float sG2s;
  __shared__ int   sCtB;
  const int b = blockIdx.x;
  const int tid = threadIdx.x;
  const int lane = tid & 63;
  const int wv = tid >> 6;

  const float* lg = logits + (size_t)b * TT * VV;

  // every wave computes len (redundant, preamble-only)
  int lsum = 0;
  const int* mrow = mask + b * TT;
#pragma unroll
  for (int k = 0; k < TT / 64; ++k) lsum += mrow[lane + (k << 6)];
#pragma unroll
  for (int off = 32; off; off >>= 1) lsum += __shfl_xor(lsum, off);
  int len = __builtin_amdgcn_readfirstlane(lsum);
  len = len < 1 ? 1 : (len > TT ? TT : len);
  const int nwin = (len + 15) >> 4;          // LSE windows (all rows < len)
  int mid = len >> 1; mid = mid < 1 ? 1 : mid;
  const int nwF = (mid + 15) >> 4;           // fwd windows: rows [0, mid)
  const int lenB = len - mid;                // rev steps: rows len-1 down to mid
  const int nwB = (lenB + 15) >> 4;

  // top-level state for the epilogue
  int lab_len = 0;
  float Ab0 = 0.0f, Ab1 = 0.0f, Ab2 = 0.0f;  // abar (fwd, emission-free pushed)
  int ctotA = 0;

#define RENORM3(X, Y, Z, CT) { \
    const float mxv = wave_max63(fmaxf(fmaxf(X, Y), Z)); \
    const int eb_ = (f2i(mxv) >> 23) & 255; \
    int kk = (eb_ > 0 && eb_ < 255) ? (187 - eb_) : 0; \
    kk = kk > 126 ? 126 : (kk < -126 ? -126 : kk); \
    CT += kk; \
    const float sc = i2f((127 + kk) << 23); \
    X *= sc; Y *= sc; Z *= sc; \
  }

#define RESCALE45(X, Y, Z, CT) { \
    const float mxv = wave_max63(fmaxf(fmaxf(X, Y), Z)); \
    const int eb_ = (f2i(mxv) >> 23) & 255; \
    int kk = (eb_ > 0 && eb_ < 255) ? (172 - eb_) : 0; \
    kk = kk > 126 ? 126 : (kk < -126 ? -126 : kk); \
    CT += kk; \
    const float sc = i2f((127 + kk) << 23); \
    X *= sc; Y *= sc; Z *= sc; \
  }

  // the one shared DP step (forward recurrence) -- used by BOTH DP waves
#define DPSTEPU(U) { \
    const float A1p = i2f(__builtin_amdgcn_update_dpp(0, f2i(A1), 0x138, 0xF, 0xF, false)); \
    const float nA0 = c##U * (A0 + A1p); \
    const float nA1 = g##U * fmaf(sk, A1p, A0 + A1); \
    A2 = c##U * (A2 + A1); \
    A0 = nA0; A1 = nA1; \
  }

#define DPSTEPM(U, BOUND) { \
    const float A1p = i2f(__builtin_amdgcn_update_dpp(0, f2i(A1), 0x138, 0xF, 0xF, false)); \
    const float nA0 = c##U * (A0 + A1p); \
    const float nA1 = g##U * fmaf(sk, A1p, A0 + A1); \
    const float nA2 = c##U * (A2 + A1); \
    const bool act = (tbase + (U)) < (BOUND); \
    A0 = act ? nA0 : A0; A1 = act ? nA1 : A1; A2 = act ? nA2 : A2; \
  }

  // shared window body: exps + readlane c-broadcast + renorm + 16 steps.
  // PREF = prefetch statement, BOUND = active-step bound.
#define DPBODY(W, S, PREF, BOUND, CT) { \
    const float cv = __builtin_amdgcn_exp2f(S##_c * LOG2E); \
    const float g0  = __builtin_amdgcn_exp2f(S##_g0  * LOG2E); \
    const float g1  = __builtin_amdgcn_exp2f(S##_g1  * LOG2E); \
    const float g2  = __builtin_amdgcn_exp2f(S##_g2  * LOG2E); \
    const float g3  = __builtin_amdgcn_exp2f(S##_g3  * LOG2E); \
    const float g4  = __builtin_amdgcn_exp2f(S##_g4  * LOG2E); \
    const float g5  = __builtin_amdgcn_exp2f(S##_g5  * LOG2E); \
    const float g6  = __builtin_amdgcn_exp2f(S##_g6  * LOG2E); \
    const float g7  = __builtin_amdgcn_exp2f(S##_g7  * LOG2E); \
    const float g8  = __builtin_amdgcn_exp2f(S##_g8  * LOG2E); \
    const float g9  = __builtin_amdgcn_exp2f(S##_g9  * LOG2E); \
    const float g10 = __builtin_amdgcn_exp2f(S##_g10 * LOG2E); \
    const float g11 = __builtin_amdgcn_exp2f(S##_g11 * LOG2E); \
    const float g12 = __builtin_amdgcn_exp2f(S##_g12 * LOG2E); \
    const float g13 = __builtin_amdgcn_exp2f(S##_g13 * LOG2E); \
    const float g14 = __builtin_amdgcn_exp2f(S##_g14 * LOG2E); \
    const float g15 = __builtin_amdgcn_exp2f(S##_g15 * LOG2E); \
    PREF \
    const float c0  = i2f(__builtin_amdgcn_readlane(f2i(cv), 0)); \
    const float c1  = i2f(__builtin_amdgcn_readlane(f2i(cv), 1)); \
    const float c2  = i2f(__builtin_amdgcn_readlane(f2i(cv), 2)); \
    const float c3  = i2f(__builtin_amdgcn_readlane(f2i(cv), 3)); \
    const float c4  = i2f(__builtin_amdgcn_readlane(f2i(cv), 4)); \
    const float c5  = i2f(__builtin_amdgcn_readlane(f2i(cv), 5)); \
    const float c6  = i2f(__builtin_amdgcn_readlane(f2i(cv), 6)); \
    const float c7  = i2f(__builtin_amdgcn_readlane(f2i(cv), 7)); \
    const float c8  = i2f(__builtin_amdgcn_readlane(f2i(cv), 8)); \
    const float c9  = i2f(__builtin_amdgcn_readlane(f2i(cv), 9)); \
    const float c10 = i2f(__builtin_amdgcn_readlane(f2i(cv), 10)); \
    const float c11 = i2f(__builtin_amdgcn_readlane(f2i(cv), 11)); \
    const float c12 = i2f(__builtin_amdgcn_readlane(f2i(cv), 12)); \
    const float c13 = i2f(__builtin_amdgcn_readlane(f2i(cv), 13)); \
    const float c14 = i2f(__builtin_amdgcn_readlane(f2i(cv), 14)); \
    const float c15 = i2f(__builtin_amdgcn_readlane(f2i(cv), 15)); \
    RENORM3(A0, A1, A2, CT) \
    const int tbase = (W) << 4; \
    if (tbase + 16 <= (BOUND)) { \
      DPSTEPU(0)  DPSTEPU(1)  DPSTEPU(2)  DPSTEPU(3) \
      DPSTEPU(4)  DPSTEPU(5)  DPSTEPU(6)  DPSTEPU(7) \
      DPSTEPU(8)  DPSTEPU(9)  DPSTEPU(10) DPSTEPU(11) \
      DPSTEPU(12) DPSTEPU(13) DPSTEPU(14) DPSTEPU(15) \
    } else { \
      DPSTEPM(0, BOUND)  DPSTEPM(1, BOUND)  DPSTEPM(2, BOUND)  DPSTEPM(3, BOUND) \
      DPSTEPM(4, BOUND)  DPSTEPM(5, BOUND)  DPSTEPM(6, BOUND)  DPSTEPM(7, BOUND) \
      DPSTEPM(8, BOUND)  DPSTEPM(9, BOUND)  DPSTEPM(10, BOUND) DPSTEPM(11, BOUND) \
      DPSTEPM(12, BOUND) DPSTEPM(13, BOUND) DPSTEPM(14, BOUND) DPSTEPM(15, BOUND) \
    } \
  }

  if (wv == 0) {
    // ================= forward DP wave: rows [0, mid) -- R7 verbatim =================
    const int lab = labels[b * LL + lane] & 63;   // label for state 2*lane+1
    lab_len = (int)__popcll(__ballot(lab != 0));
    const int plab = __builtin_amdgcn_update_dpp(0, lab, 0x138, 0xF, 0xF, false);
    const float sk = (lab != 0 && lab != plab) ? 1.0f : 0.0f; // allow_skip
    float A0 = (lane == 0) ? 1.0f : 0.0f;         // t=0 runs as a normal step
    float A1 = 0.0f, A2 = 0.0f;
    __builtin_amdgcn_s_setprio(1);

    const int cu = lane & 15;
    const float* lgg = lg + lab;                  // per-lane gather base
    const float* lgc = lg + (cu << 6);            // lane u<16 -> row u, col 0

    float qa_c, qb_c, qc_c;
    float qa_g0, qa_g1, qa_g2, qa_g3, qa_g4, qa_g5, qa_g6, qa_g7,
          qa_g8, qa_g9, qa_g10, qa_g11, qa_g12, qa_g13, qa_g14, qa_g15;
    float qb_g0, qb_g1, qb_g2, qb_g3, qb_g4, qb_g5, qb_g6, qb_g7,
          qb_g8, qb_g9, qb_g10, qb_g11, qb_g12, qb_g13, qb_g14, qb_g15;
    float qc_g0, qc_g1, qc_g2, qc_g3, qc_g4, qc_g5, qc_g6, qc_g7,
          qc_g8, qc_g9, qc_g10, qc_g11, qc_g12, qc_g13, qc_g14, qc_g15;

#define FISSUE(WN, S) { \
    const float* pg_ = lgg + ((WN) << 10); \
    S##_g0  = pg_[0];    S##_g1  = pg_[64];   S##_g2  = pg_[128];  S##_g3  = pg_[192]; \
    S##_g4  = pg_[256];  S##_g5  = pg_[320];  S##_g6  = pg_[384];  S##_g7  = pg_[448]; \
    S##_g8  = pg_[512];  S##_g9  = pg_[576];  S##_g10 = pg_[640];  S##_g11 = pg_[704]; \
    S##_g12 = pg_[768];  S##_g13 = pg_[832];  S##_g14 = pg_[896];  S##_g15 = pg_[960]; \
    S##_c = lgc[(WN) << 10]; \
  }

    FISSUE(0, qa) FISSUE(1, qb) FISSUE(2, qc)
    int w = 0;
    for (; w + 3 <= nwF; w += 3) {
      DPBODY(w,     qa, { if (w + 3 < 64) { FISSUE(w + 3, qa) } }, mid, ctotA)
      DPBODY(w + 1, qb, { if (w + 4 < 64) { FISSUE(w + 4, qb) } }, mid, ctotA)
      DPBODY(w + 2, qc, { if (w + 5 < 64) { FISSUE(w + 5, qc) } }, mid, ctotA)
    }
    if (w < nwF) { DPBODY(w, qa, { if (w + 3 < 64) { FISSUE(w + 3, qa) } }, mid, ctotA) ++w; }
    if (w < nwF) { DPBODY(w, qb, { if (w + 3 < 64) { FISSUE(w + 3, qb) } }, mid, ctotA) ++w; }
#undef FISSUE
    RESCALE45(A0, A1, A2, ctotA)
    // abar: push alpha through one emission-free transition (epilogue-only)
    const float A1p = i2f(__builtin_amdgcn_update_dpp(0, f2i(A1), 0x138, 0xF, 0xF, false));
    Ab0 = A0 + A1p;                    // abar(2l)   = A0 + A1[l-1]
    Ab1 = fmaf(sk, A1p, A0 + A1);      // abar(2l+1) = A1 + A0 + sk*A1[l-1]
    Ab2 = A2 + A1;                     // abar(128), valid on lane 63

  } else if (wv == 1) {
    // ======= reversed-forward DP wave: orig rows len-1 down to mid, fwd code =======
    const int lab0 = labels[b * LL + lane] & 63;
    const int ll = (int)__popcll(__ballot(lab0 != 0));
    int rlab = 0;
    if (lane < ll) rlab = labels[b * LL + (ll - 1 - lane)] & 63;   // reversed labels
    const int plab = __builtin_amdgcn_update_dpp(0, rlab, 0x138, 0xF, 0xF, false);
    const float sk = (rlab != 0 && rlab != plab) ? 1.0f : 0.0f;    // rev allow_skip
    float A0 = (lane == 0) ? (ll == 0 ? 2.0f : 1.0f) : 0.0f;       // ll==0 double-count
    float A1 = 0.0f, A2 = 0.0f;
    int ctotB = 0;
    __builtin_amdgcn_s_setprio(1);

    const int cu = lane & 15;
    const float* lgg = lg + rlab;      // per-lane gather base (reversed labels)
    const int lenm1 = len - 1;

    float qa_c, qb_c, qc_c;
    float qa_g0, qa_g1, qa_g2, qa_g3, qa_g4, qa_g5, qa_g6, qa_g7,
          qa_g8, qa_g9, qa_g10, qa_g11, qa_g12, qa_g13, qa_g14, qa_g15;
    float qb_g0, qb_g1, qb_g2, qb_g3, qb_g4, qb_g5, qb_g6, qb_g7,
          qb_g8, qb_g9, qb_g10, qb_g11, qb_g12, qb_g13, qb_g14, qb_g15;
    float qc_g0, qc_g1, qc_g2, qc_g3, qc_g4, qc_g5, qc_g6, qc_g7,
          qc_g8, qc_g9, qc_g10, qc_g11, qc_g12, qc_g13, qc_g14, qc_g15;

    // rev window WN, step U -> orig row (len-1 - 16*WN - U): negative
    // compile-time offsets from a per-window base; base clamped to >=15 so
    // all 16 rows stay >=0 (clamped windows are beyond lenB -> steps frozen).
#define RISSUE(WN, S) { \
    int br_ = lenm1 - ((WN) << 4); \
    br_ = br_ < 15 ? 15 : br_; \
    const float* pg_ = lgg + ((size_t)br_ << 6); \
    S##_g0  = pg_[0];     S##_g1  = pg_[-64];   S##_g2  = pg_[-128];  S##_g3  = pg_[-192]; \
    S##_g4  = pg_[-256];  S##_g5  = pg_[-320];  S##_g6  = pg_[-384];  S##_g7  = pg_[-448]; \
    S##_g8  = pg_[-512];  S##_g9  = pg_[-576];  S##_g10 = pg_[-640];  S##_g11 = pg_[-704]; \
    S##_g12 = pg_[-768];  S##_g13 = pg_[-832];  S##_g14 = pg_[-896];  S##_g15 = pg_[-960]; \
    S##_c = lg[(br_ - cu) << 6]; \
  }

    RISSUE(0, qa) RISSUE(1, qb) RISSUE(2, qc)
    int w = 0;
    for (; w + 3 <= nwB; w += 3) {
      DPBODY(w,     qa, { RISSUE(w + 3, qa) }, lenB, ctotB)
      DPBODY(w + 1, qb, { RISSUE(w + 4, qb) }, lenB, ctotB)
      DPBODY(w + 2, qc, { RISSUE(w + 5, qc) }, lenB, ctotB)
    }
    if (w < nwB) { DPBODY(w, qa, { RISSUE(w + 3, qa) }, lenB, ctotB) ++w; }
    if (w < nwB) { DPBODY(w, qb, { RISSUE(w + 3, qb) }, lenB, ctotB) ++w; }
#undef RISSUE
    RESCALE45(A0, A1, A2, ctotB)

    sG0v[lane] = A0;                   // arev even states 2*lane
    sG1v[lane] = A1;                   // arev odd states 2*lane+1
    if (lane == 63) sG2s = A2;         // arev state 128
    if (lane == 0) sCtB = ctotB;

  } else {
    // ================= LSE waves (2..5): async row-LSE streaming (R7 verbatim) =================
    const int pw = wv - 2;
    const int prow = lane >> 4;
    const int pcol = (lane & 15) << 2;
    const float* pb_ = lg + ((((pw << 2) + prow) << 6) + pcol);
    float acc = 0.0f;
    float4 pa, pb, pc;

#define LISSUE(K, S) { S = *(const float4*)(pb_ + ((K) << 10)); }

#define LBODY(K, S) { \
    const float e0 = __builtin_amdgcn_exp2f(S.x * LOG2E); \
    const float e1 = __builtin_amdgcn_exp2f(S.y * LOG2E); \
    const float e2 = __builtin_amdgcn_exp2f(S.z * LOG2E); \
    const float e3 = __builtin_amdgcn_exp2f(S.w * LOG2E); \
    if ((K) + 3 < 64) { LISSUE((K) + 3, S) } \
    float s = (e0 + e1) + (e2 + e3); \
    s += i2f(__builtin_amdgcn_update_dpp(0, f2i(s), 0x111, 0xF, 0xF, true)); \
    s += i2f(__builtin_amdgcn_update_dpp(0, f2i(s), 0x112, 0xF, 0xF, true)); \
    s += i2f(__builtin_amdgcn_update_dpp(0, f2i(s), 0x114, 0xF, 0xF, true)); \
    s += i2f(__builtin_amdgcn_update_dpp(0, f2i(s), 0x118, 0xF, 0xF, true)); \
    if ((lane & 15) == 15 && ((((K) << 4) + (pw << 2) + prow) < len)) acc += __logf(s); \
  }

    LISSUE(0, pa) LISSUE(1, pb) LISSUE(2, pc)
    int k = 0;
    for (; k + 3 <= nwin; k += 3) {
      LBODY(k, pa) LBODY(k + 1, pb) LBODY(k + 2, pc)
    }
    if (k < nwin) { LBODY(k, pa) ++k; }
    if (k < nwin) { LBODY(k, pb) ++k; }
#undef LBODY
#undef LISSUE

    float a = ((lane & 15) == 15) ? acc : 0.0f;
    a += __shfl_xor(a, 16);
    a += __shfl_xor(a, 32);
    if (lane == 63) lsePart[pw] = a;
  }

  __syncthreads();   // single block-wide sync of the whole kernel

  if (wv == 0) {
    // p = sum_s' abar(s') * arev(2*ll - s'), via LDS index-reverse.
    const int llv = lab_len;
    const int i0 = llv - lane;         // abar(2l) pairs arev even state 2*(ll-l)
    const int i1 = llv - 1 - lane;     // abar(2l+1) pairs arev odd state 2*(ll-l-1)+1
    float t0 = 0.0f;
    if (i0 >= 0 && i0 < 64) t0 = sG0v[i0];
    else if (i0 == 64)      t0 = sG2s;           // l=0, ll=64: arev(128)
    const float t1 = (i1 >= 0) ? sG1v[i1] : 0.0f;
    float prod = Ab0 * t0 + Ab1 * t1;
    if (lane == 63 && llv == 64) prod = fmaf(Ab2, sG0v[0], prod);  // abar(128)*arev(0)
#pragma unroll
    for (int off = 32; off; off >>= 1) prod += __shfl_xor(prod, off);
    const float p = fmaxf(prod, 1e-37f);   // guard: never log(0) -> inf poisoning
    float loss = ((lsePart[0] + lsePart[1]) + (lsePart[2] + lsePart[3]))
               - LN2 * (__builtin_amdgcn_logf(p) - (float)(ctotA + sCtB));
    if (lab_len > len) loss = 0.0f;  // feasibility mask
    if (lane == 0) atomicAdd(out, loss * (1.0f / 256.0f));
  }
#undef DPBODY
#undef DPSTEPM
#undef DPSTEPU
#undef RESCALE45
#undef RENORM3
}

extern "C" void kernel_launch(void* const* d_in, const int* in_sizes, int n_in,
                              void* d_out, int out_size, void* d_ws, size_t ws_size,
                              hipStream_t stream) {
  (void)in_sizes; (void)n_in; (void)out_size; (void)d_ws; (void)ws_size;
  hipMemsetAsync(d_out, 0, sizeof(float), stream);   // d_out is poisoned 0xAA
  ctc_fused<<<dim3(BB), dim3(384), 0, stream>>>(
      (const int*)d_in[0], (const float*)d_in[1], (const int*)d_in[2], (float*)d_out);
}